// Round 2
// baseline (240.567 us; speedup 1.0000x reference)
//
#include <hip/hip_runtime.h>
#include <stdint.h>

#define Bb 2
#define Ss 2048
#define Dd 1024
#define Hh 16
#define HDd 64
// M = B*S = 4096

typedef float f32x4 __attribute__((ext_vector_type(4)));
typedef __bf16 bf16x8 __attribute__((ext_vector_type(8)));
typedef short s16x8 __attribute__((ext_vector_type(8)));

__device__ inline unsigned short f2bf(float f) {
  unsigned u = __builtin_bit_cast(unsigned, f);
  u += 0x7fffu + ((u >> 16) & 1u);
  return (unsigned short)(u >> 16);
}
__device__ inline float bf2f(unsigned short h) {
  unsigned u = ((unsigned)h) << 16;
  return __builtin_bit_cast(float, u);
}

// ---------------- cast fp32 -> bf16, vectorized ----------------
__global__ void cast_f32_bf16(const float* __restrict__ src,
                              unsigned short* __restrict__ dst, int n4) {
  int i = blockIdx.x * blockDim.x + threadIdx.x;
  if (i < n4) {
    float4 v = ((const float4*)src)[i];
    ushort4 o;
    o.x = f2bf(v.x); o.y = f2bf(v.y); o.z = f2bf(v.z); o.w = f2bf(v.w);
    ((ushort4*)dst)[i] = o;
  }
}

// ---------------- GEMM: C[M,N] = A[M,K] * Bw[N,K]^T + bias ----------------
// 128x128 tile, BK=32, 4 waves (2x2), 4x4 16x16x32 frags per wave.
template <bool OUT_BF16>
__global__ __launch_bounds__(256) void gemm_bt(
    const unsigned short* __restrict__ A, const unsigned short* __restrict__ Bw,
    const float* __restrict__ bias, void* __restrict__ Cout,
    int M, int N, int K) {
  __shared__ __align__(16) unsigned short As[128 * 32];
  __shared__ __align__(16) unsigned short Bs[128 * 32];
  const int tid = threadIdx.x;
  const int w = tid >> 6, l = tid & 63;
  const int lg = l >> 4, lr = l & 15;
  const int mbase = blockIdx.y * 128, nbase = blockIdx.x * 128;
  const int wr = w >> 1, wc = w & 1;
  f32x4 acc[4][4] = {};

  for (int k0 = 0; k0 < K; k0 += 32) {
#pragma unroll
    for (int r = 0; r < 2; ++r) {
      int c = r * 256 + w * 64 + l;      // chunk id, lane-linear within wave
      int row = c >> 2, c8 = c & 3;
      const unsigned short* ga = A + (size_t)(mbase + row) * K + k0 + c8 * 8;
      __builtin_amdgcn_global_load_lds(
          (const __attribute__((address_space(1))) void*)ga,
          (__attribute__((address_space(3))) void*)(As + c * 8), 16, 0, 0);
      const unsigned short* gb = Bw + (size_t)(nbase + row) * K + k0 + c8 * 8;
      __builtin_amdgcn_global_load_lds(
          (const __attribute__((address_space(1))) void*)gb,
          (__attribute__((address_space(3))) void*)(Bs + c * 8), 16, 0, 0);
    }
    __syncthreads();
    bf16x8 af[4], bfr[4];
#pragma unroll
    for (int mi = 0; mi < 4; ++mi)
      af[mi] = *(const bf16x8*)(As + (wr * 64 + mi * 16 + lr) * 32 + lg * 8);
#pragma unroll
    for (int ni = 0; ni < 4; ++ni)
      bfr[ni] = *(const bf16x8*)(Bs + (wc * 64 + ni * 16 + lr) * 32 + lg * 8);
#pragma unroll
    for (int mi = 0; mi < 4; ++mi)
#pragma unroll
      for (int ni = 0; ni < 4; ++ni)
        acc[mi][ni] = __builtin_amdgcn_mfma_f32_16x16x32_bf16(
            af[mi], bfr[ni], acc[mi][ni], 0, 0, 0);
    __syncthreads();
  }

#pragma unroll
  for (int mi = 0; mi < 4; ++mi) {
#pragma unroll
    for (int ni = 0; ni < 4; ++ni) {
      int col = nbase + wc * 64 + ni * 16 + lr;
      float bi = bias[col];
#pragma unroll
      for (int r = 0; r < 4; ++r) {
        int row = mbase + wr * 64 + mi * 16 + lg * 4 + r;
        float v = acc[mi][ni][r] + bi;
        if (OUT_BF16)
          ((unsigned short*)Cout)[(size_t)row * N + col] = f2bf(v);
        else
          ((float*)Cout)[(size_t)row * N + col] = v;
      }
    }
  }
}

// ---------------- RoPE in-place on q,k halves of qkv ----------------
// qkv: [4096][3072] bf16. One thread per (row, pair) over q and k sections.
__global__ void rope_inplace(unsigned short* __restrict__ qkv,
                             const float* __restrict__ fc,
                             const float* __restrict__ fs) {
  int j = blockIdx.x * blockDim.x + threadIdx.x;   // [0, 4096*1024)
  int m = j >> 10;
  int rr = j & 1023;
  int t = rr >> 9;          // 0 = q, 1 = k
  int pp = rr & 511;
  int h = pp >> 5, p = pp & 31;
  int s = m & (Ss - 1);
  int col = t * 1024 + h * 64 + 2 * p;
  unsigned* addr = (unsigned*)(qkv + (size_t)m * 3072 + col);
  unsigned u = *addr;
  float x0 = bf2f((unsigned short)(u & 0xffff));
  float x1 = bf2f((unsigned short)(u >> 16));
  float c = fc[s * 32 + p], sn = fs[s * 32 + p];
  float o0 = x0 * c - x1 * sn;
  float o1 = x0 * sn + x1 * c;
  *addr = (unsigned)f2bf(o0) | ((unsigned)f2bf(o1) << 16);
}

// ---------------- V transpose: qkv v-part -> vt[b,h,d,s] ----------------
// 64x64 tile per block; 256 threads x 16 elements each.
__global__ __launch_bounds__(256) void transpose_v(
    const unsigned short* __restrict__ qkv, unsigned short* __restrict__ vt) {
  __shared__ __align__(16) unsigned short tile[64][72];
  int s0 = blockIdx.x * 64;
  int bh = blockIdx.y;
  int b = bh >> 4, h = bh & 15;
  int t = threadIdx.x;
  int r = t >> 2, c0 = (t & 3) * 16;
  const unsigned short* src =
      qkv + (size_t)(b * Ss + s0 + r) * 3072 + 2048 + h * 64 + c0;
  *(s16x8*)&tile[r][c0]     = *(const s16x8*)src;
  *(s16x8*)&tile[r][c0 + 8] = *(const s16x8*)(src + 8);
  __syncthreads();
  unsigned short tmp[16];
#pragma unroll
  for (int i = 0; i < 16; ++i) tmp[i] = tile[c0 + i][r];
  unsigned short* dst = vt + ((size_t)bh * 64 + r) * Ss + s0 + c0;
  *(s16x8*)dst       = *(const s16x8*)tmp;
  *(s16x8*)(dst + 8) = *(const s16x8*)(tmp + 8);
}

// ---------------- Flash attention (causal) ----------------
// grid: (S/128 [reversed], B*H). block: 256 = 4 waves; wave owns 32 q-rows.
__global__ __launch_bounds__(256) void attn(
    const unsigned short* __restrict__ qkv, const unsigned short* __restrict__ vt,
    unsigned short* __restrict__ ctx) {
  __shared__ __align__(16) unsigned short Ks[64 * 72];
  __shared__ __align__(16) unsigned short Vs[64 * 72];
  __shared__ __align__(16) unsigned short Ps[4][32 * 72];
  int qi = gridDim.x - 1 - blockIdx.x;   // heavy tiles first
  int bh = blockIdx.y;
  int b = bh >> 4, h = bh & 15;
  int qbase = qi * 128;
  int tid = threadIdx.x;
  int w = tid >> 6, l = tid & 63;
  int lg = l >> 4, lr = l & 15;

  // Q fragments (held for the whole kernel)
  bf16x8 qa[2][2];
#pragma unroll
  for (int mi = 0; mi < 2; ++mi)
#pragma unroll
    for (int kc = 0; kc < 2; ++kc) {
      const unsigned short* g =
          qkv + (size_t)(b * Ss + qbase + w * 32 + mi * 16 + lr) * 3072 +
          h * 64 + kc * 32 + lg * 8;
      qa[mi][kc] = *(const bf16x8*)g;
    }

  f32x4 acc[2][4] = {};
  float mrow[2][4], lrow[2][4];
#pragma unroll
  for (int mi = 0; mi < 2; ++mi)
#pragma unroll
    for (int r = 0; r < 4; ++r) { mrow[mi][r] = -1e30f; lrow[mi][r] = 0.f; }

  int nkt = 2 * qi + 2;
  for (int kt = 0; kt < nkt; ++kt) {
    int kbase = kt * 64;
    {
      // full 64x64 tiles: 256 threads x 16 elements
      int row = tid >> 2, c0 = (tid & 3) * 16;
      const unsigned short* gk =
          qkv + (size_t)(b * Ss + kbase + row) * 3072 + 1024 + h * 64 + c0;
      *(s16x8*)&Ks[row * 72 + c0]     = *(const s16x8*)gk;
      *(s16x8*)&Ks[row * 72 + c0 + 8] = *(const s16x8*)(gk + 8);
      const unsigned short* gv =
          vt + ((size_t)bh * 64 + row) * Ss + kbase + c0;
      *(s16x8*)&Vs[row * 72 + c0]     = *(const s16x8*)gv;
      *(s16x8*)&Vs[row * 72 + c0 + 8] = *(const s16x8*)(gv + 8);
    }
    __syncthreads();

    // S = Q K^T
    f32x4 sfr[2][4] = {};
#pragma unroll
    for (int kc = 0; kc < 2; ++kc) {
      bf16x8 kb[4];
#pragma unroll
      for (int ni = 0; ni < 4; ++ni)
        kb[ni] = *(const bf16x8*)&Ks[(ni * 16 + lr) * 72 + kc * 32 + lg * 8];
#pragma unroll
      for (int mi = 0; mi < 2; ++mi)
#pragma unroll
        for (int ni = 0; ni < 4; ++ni)
          sfr[mi][ni] = __builtin_amdgcn_mfma_f32_16x16x32_bf16(
              qa[mi][kc], kb[ni], sfr[mi][ni], 0, 0, 0);
    }

    const bool maskTile = (kbase + 63) > (qbase + w * 32);
#pragma unroll
    for (int mi = 0; mi < 2; ++mi) {
      float sv[4][4];
      float tmax[4];
#pragma unroll
      for (int r = 0; r < 4; ++r) tmax[r] = -1e30f;
#pragma unroll
      for (int ni = 0; ni < 4; ++ni)
#pragma unroll
        for (int r = 0; r < 4; ++r) {
          float s = sfr[mi][ni][r] * 0.125f;
          if (maskTile) {
            int row = qbase + w * 32 + mi * 16 + lg * 4 + r;
            int col = kbase + ni * 16 + lr;
            if (col > row) s = -1e30f;
          }
          sv[ni][r] = s;
          tmax[r] = fmaxf(tmax[r], s);
        }
#pragma unroll
      for (int r = 0; r < 4; ++r) {
#pragma unroll
        for (int off = 8; off >= 1; off >>= 1)
          tmax[r] = fmaxf(tmax[r], __shfl_xor(tmax[r], off));
        float mnew = fmaxf(mrow[mi][r], tmax[r]);
        float alpha = __expf(mrow[mi][r] - mnew);
        mrow[mi][r] = mnew;
        float tsum = 0.f;
#pragma unroll
        for (int ni = 0; ni < 4; ++ni) {
          float p = __expf(sv[ni][r] - mnew);
          sv[ni][r] = p;
          tsum += p;
        }
#pragma unroll
        for (int off = 8; off >= 1; off >>= 1) tsum += __shfl_xor(tsum, off);
        lrow[mi][r] = lrow[mi][r] * alpha + tsum;
#pragma unroll
        for (int ni = 0; ni < 4; ++ni) acc[mi][ni][r] *= alpha;
      }
      // P -> LDS (bf16) for A-fragment reload
#pragma unroll
      for (int ni = 0; ni < 4; ++ni)
#pragma unroll
        for (int r = 0; r < 4; ++r)
          Ps[w][(mi * 16 + lg * 4 + r) * 72 + ni * 16 + lr] = f2bf(sv[ni][r]);
    }

    // ctx += P V
#pragma unroll
    for (int kc = 0; kc < 2; ++kc) {
      bf16x8 pa[2];
#pragma unroll
      for (int mi = 0; mi < 2; ++mi)
        pa[mi] = *(const bf16x8*)&Ps[w][(mi * 16 + lr) * 72 + kc * 32 + lg * 8];
#pragma unroll
      for (int ni = 0; ni < 4; ++ni) {
        bf16x8 vb = *(const bf16x8*)&Vs[(ni * 16 + lr) * 72 + kc * 32 + lg * 8];
#pragma unroll
        for (int mi = 0; mi < 2; ++mi)
          acc[mi][ni] = __builtin_amdgcn_mfma_f32_16x16x32_bf16(
              pa[mi], vb, acc[mi][ni], 0, 0, 0);
      }
    }
    __syncthreads();
  }

  // epilogue: ctx row / l, write bf16 [B,S,H*HD]
#pragma unroll
  for (int mi = 0; mi < 2; ++mi) {
    float inv[4];
#pragma unroll
    for (int r = 0; r < 4; ++r) inv[r] = 1.0f / lrow[mi][r];
#pragma unroll
    for (int ni = 0; ni < 4; ++ni)
#pragma unroll
      for (int r = 0; r < 4; ++r) {
        int row = qbase + w * 32 + mi * 16 + lg * 4 + r;
        int col = h * 64 + ni * 16 + lr;
        ctx[(size_t)(b * Ss + row) * 1024 + col] = f2bf(acc[mi][ni][r] * inv[r]);
      }
  }
}

extern "C" void kernel_launch(void* const* d_in, const int* in_sizes, int n_in,
                              void* d_out, int out_size, void* d_ws, size_t ws_size,
                              hipStream_t stream) {
  const float* x       = (const float*)d_in[0];
  const float* w_qkv   = (const float*)d_in[1];
  const float* b_qkv   = (const float*)d_in[2];
  const float* w_dense = (const float*)d_in[3];
  const float* b_dense = (const float*)d_in[4];
  const float* fc      = (const float*)d_in[5];
  const float* fs      = (const float*)d_in[6];
  float* out = (float*)d_out;

  char* ws = (char*)d_ws;
  // layout (48 MB total): xb also reused as ctx (bf16) after GEMM1 consumes it
  unsigned short* xb    = (unsigned short*)(ws);                        // 8 MB
  unsigned short* wqkvb = (unsigned short*)(ws + (8ull  << 20));        // 6 MB
  unsigned short* wdb   = (unsigned short*)(ws + (14ull << 20));        // 2 MB
  unsigned short* qkvb  = (unsigned short*)(ws + (16ull << 20));        // 24 MB
  unsigned short* vt    = (unsigned short*)(ws + (40ull << 20));        // 8 MB

  cast_f32_bf16<<<4096, 256, 0, stream>>>(x, xb, (Bb * Ss * Dd) / 4);
  cast_f32_bf16<<<3072, 256, 0, stream>>>(w_qkv, wqkvb, (3 * Dd * Dd) / 4);
  cast_f32_bf16<<<1024, 256, 0, stream>>>(w_dense, wdb, (Dd * Dd) / 4);

  gemm_bt<true><<<dim3(24, 32), 256, 0, stream>>>(xb, wqkvb, b_qkv, qkvb,
                                                  4096, 3072, 1024);
  rope_inplace<<<(Bb * Ss * Dd) / 256, 256, 0, stream>>>(qkvb, fc, fs);
  transpose_v<<<dim3(32, 32), 256, 0, stream>>>(qkvb, vt);
  attn<<<dim3(16, 32), 256, 0, stream>>>(qkvb, vt, xb /* ctx reuse */);
  gemm_bt<false><<<dim3(8, 32), 256, 0, stream>>>(xb, wdb, b_dense, out,
                                                  4096, 1024, 1024);
}

// Round 4
// 173.189 us; speedup vs baseline: 1.3890x; 1.3890x over previous
//
#include <hip/hip_runtime.h>
#include <stdint.h>

#define Bb 2
#define Ss 2048
#define Dd 1024
#define Hh 16
#define HDd 64
// M = B*S = 4096

typedef float f32x4 __attribute__((ext_vector_type(4)));
typedef __bf16 bf16x8 __attribute__((ext_vector_type(8)));
typedef short s16x8 __attribute__((ext_vector_type(8)));

__device__ inline unsigned short f2bf(float f) {
  unsigned u = __builtin_bit_cast(unsigned, f);
  u += 0x7fffu + ((u >> 16) & 1u);
  return (unsigned short)(u >> 16);
}
__device__ inline float bf2f(unsigned short h) {
  unsigned u = ((unsigned)h) << 16;
  return __builtin_bit_cast(float, u);
}
__device__ inline unsigned pk2(float a, float b) {
  return (unsigned)f2bf(a) | ((unsigned)f2bf(b) << 16);
}

// ---------------- cast fp32 -> bf16, vectorized ----------------
__global__ void cast_f32_bf16(const float* __restrict__ src,
                              unsigned short* __restrict__ dst, int n4) {
  int i = blockIdx.x * blockDim.x + threadIdx.x;
  if (i < n4) {
    float4 v = ((const float4*)src)[i];
    ushort4 o;
    o.x = f2bf(v.x); o.y = f2bf(v.y); o.z = f2bf(v.z); o.w = f2bf(v.w);
    ((ushort4*)dst)[i] = o;
  }
}

// ---------------- GEMM: C[M,N] = A[M,K] * Bw[N,K]^T + bias ----------------
template <bool OUT_BF16>
__global__ __launch_bounds__(256) void gemm_bt(
    const unsigned short* __restrict__ A, const unsigned short* __restrict__ Bw,
    const float* __restrict__ bias, void* __restrict__ Cout,
    int M, int N, int K) {
  __shared__ __align__(16) unsigned short As[128 * 32];
  __shared__ __align__(16) unsigned short Bs[128 * 32];
  const int tid = threadIdx.x;
  const int w = tid >> 6, l = tid & 63;
  const int lg = l >> 4, lr = l & 15;
  const int mbase = blockIdx.y * 128, nbase = blockIdx.x * 128;
  const int wr = w >> 1, wc = w & 1;
  f32x4 acc[4][4] = {};

  for (int k0 = 0; k0 < K; k0 += 32) {
#pragma unroll
    for (int r = 0; r < 2; ++r) {
      int c = r * 256 + w * 64 + l;
      int row = c >> 2, c8 = c & 3;
      const unsigned short* ga = A + (size_t)(mbase + row) * K + k0 + c8 * 8;
      __builtin_amdgcn_global_load_lds(
          (const __attribute__((address_space(1))) void*)ga,
          (__attribute__((address_space(3))) void*)(As + c * 8), 16, 0, 0);
      const unsigned short* gb = Bw + (size_t)(nbase + row) * K + k0 + c8 * 8;
      __builtin_amdgcn_global_load_lds(
          (const __attribute__((address_space(1))) void*)gb,
          (__attribute__((address_space(3))) void*)(Bs + c * 8), 16, 0, 0);
    }
    __syncthreads();
    bf16x8 af[4], bfr[4];
#pragma unroll
    for (int mi = 0; mi < 4; ++mi)
      af[mi] = *(const bf16x8*)(As + (wr * 64 + mi * 16 + lr) * 32 + lg * 8);
#pragma unroll
    for (int ni = 0; ni < 4; ++ni)
      bfr[ni] = *(const bf16x8*)(Bs + (wc * 64 + ni * 16 + lr) * 32 + lg * 8);
#pragma unroll
    for (int mi = 0; mi < 4; ++mi)
#pragma unroll
      for (int ni = 0; ni < 4; ++ni)
        acc[mi][ni] = __builtin_amdgcn_mfma_f32_16x16x32_bf16(
            af[mi], bfr[ni], acc[mi][ni], 0, 0, 0);
    __syncthreads();
  }

#pragma unroll
  for (int mi = 0; mi < 4; ++mi) {
#pragma unroll
    for (int ni = 0; ni < 4; ++ni) {
      int col = nbase + wc * 64 + ni * 16 + lr;
      float bi = bias[col];
#pragma unroll
      for (int r = 0; r < 4; ++r) {
        int row = mbase + wr * 64 + mi * 16 + lg * 4 + r;
        float v = acc[mi][ni][r] + bi;
        if (OUT_BF16)
          ((unsigned short*)Cout)[(size_t)row * N + col] = f2bf(v);
        else
          ((float*)Cout)[(size_t)row * N + col] = v;
      }
    }
  }
}

// ---------------- RoPE in-place on q,k halves of qkv ----------------
__global__ void rope_inplace(unsigned short* __restrict__ qkv,
                             const float* __restrict__ fc,
                             const float* __restrict__ fs) {
  int j = blockIdx.x * blockDim.x + threadIdx.x;
  int m = j >> 10;
  int rr = j & 1023;
  int t = rr >> 9;
  int pp = rr & 511;
  int h = pp >> 5, p = pp & 31;
  int s = m & (Ss - 1);
  int col = t * 1024 + h * 64 + 2 * p;
  unsigned* addr = (unsigned*)(qkv + (size_t)m * 3072 + col);
  unsigned u = *addr;
  float x0 = bf2f((unsigned short)(u & 0xffff));
  float x1 = bf2f((unsigned short)(u >> 16));
  float c = fc[s * 32 + p], sn = fs[s * 32 + p];
  float o0 = x0 * c - x1 * sn;
  float o1 = x0 * sn + x1 * c;
  *addr = (unsigned)f2bf(o0) | ((unsigned)f2bf(o1) << 16);
}

// ---------------- V transpose: qkv v-part -> vt[b,h,d,s] ----------------
__global__ __launch_bounds__(256) void transpose_v(
    const unsigned short* __restrict__ qkv, unsigned short* __restrict__ vt) {
  __shared__ __align__(16) unsigned short tile[64][72];
  int s0 = blockIdx.x * 64;
  int bh = blockIdx.y;
  int b = bh >> 4, h = bh & 15;
  int t = threadIdx.x;
  int r = t >> 2, c0 = (t & 3) * 16;
  const unsigned short* src =
      qkv + (size_t)(b * Ss + s0 + r) * 3072 + 2048 + h * 64 + c0;
  *(s16x8*)&tile[r][c0]     = *(const s16x8*)src;
  *(s16x8*)&tile[r][c0 + 8] = *(const s16x8*)(src + 8);
  __syncthreads();
  unsigned short tmp[16];
#pragma unroll
  for (int i = 0; i < 16; ++i) tmp[i] = tile[c0 + i][r];
  unsigned short* dst = vt + ((size_t)bh * 64 + r) * Ss + s0 + c0;
  *(s16x8*)dst       = *(const s16x8*)tmp;
  *(s16x8*)(dst + 8) = *(const s16x8*)(tmp + 8);
}

// ---------------- Flash attention (causal), swapped-QK^T form ----------------
// grid: (S/128 [reversed], B*H). block: 256 = 4 waves; wave owns 32 q-rows.
// S^T = K·Q^T (lane owns a q-row, k in regs) -> in-lane softmax ->
// P packed b64 -> LDS (stride 72!) -> PV: ctx^T = V^T·P^T.
// K/V double-buffered, reg-staged (T14), one barrier per k-tile.
__global__ __launch_bounds__(256, 2) void attn(
    const unsigned short* __restrict__ qkv, const unsigned short* __restrict__ vt,
    unsigned short* __restrict__ ctx) {
  __shared__ __align__(16) unsigned short Ks[2][64 * 72];
  __shared__ __align__(16) unsigned short Vs[2][64 * 72];
  __shared__ __align__(16) unsigned short Ps[4][32 * 72];  // 32 q x 64 k, stride 72
  int qi = gridDim.x - 1 - blockIdx.x;   // heavy tiles first
  int bh = blockIdx.y;
  int b = bh >> 4, h = bh & 15;
  int qbase = qi * 128;
  int tid = threadIdx.x;
  int w = tid >> 6, l = tid & 63;
  int lg = l >> 4, lr = l & 15;

  // Q fragments (B-operand: col=q on lanes, k=d in regs)
  bf16x8 qb[2][2];
#pragma unroll
  for (int mi = 0; mi < 2; ++mi)
#pragma unroll
    for (int kc = 0; kc < 2; ++kc) {
      const unsigned short* g =
          qkv + (size_t)(b * Ss + qbase + w * 32 + mi * 16 + lr) * 3072 +
          h * 64 + kc * 32 + lg * 8;
      qb[mi][kc] = *(const bf16x8*)g;
    }

  // staging: thread covers K row srow cols [c0,c0+16) and same for V^T
  int srow = tid >> 2, c0 = (tid & 3) * 16;
  const unsigned short* kptr =
      qkv + ((size_t)(b * Ss) + srow) * 3072 + 1024 + h * 64 + c0;
  const unsigned short* vptr = vt + ((size_t)bh * 64 + srow) * 2048 + c0;

  int nkt = 2 * qi + 2;
  s16x8 rk0, rk1, rv0, rv1;
  // tile 0 -> buf 0
  rk0 = *(const s16x8*)kptr;  rk1 = *(const s16x8*)(kptr + 8);
  rv0 = *(const s16x8*)vptr;  rv1 = *(const s16x8*)(vptr + 8);
  *(s16x8*)&Ks[0][srow * 72 + c0]     = rk0;
  *(s16x8*)&Ks[0][srow * 72 + c0 + 8] = rk1;
  *(s16x8*)&Vs[0][srow * 72 + c0]     = rv0;
  *(s16x8*)&Vs[0][srow * 72 + c0 + 8] = rv1;
  // issue tile 1 loads
  {
    const unsigned short* gk = kptr + (size_t)64 * 3072;
    const unsigned short* gv = vptr + 64;
    rk0 = *(const s16x8*)gk;  rk1 = *(const s16x8*)(gk + 8);
    rv0 = *(const s16x8*)gv;  rv1 = *(const s16x8*)(gv + 8);
  }
  __syncthreads();

  f32x4 acc[4][2] = {};          // acc[nd][mi]: ctx^T, rows d, cols q
  float mrow[2] = {-1e30f, -1e30f}, lrow[2] = {0.f, 0.f};

  int p = 0;
  for (int kt = 0; kt < nkt; ++kt) {
    int kbase = kt * 64;
    if (kbase <= qbase + w * 32 + 31) {     // wave-uniform skip of dead tiles
      // S^T = K Q^T
      f32x4 st[4][2] = {};
#pragma unroll
      for (int kc = 0; kc < 2; ++kc) {
        bf16x8 ka[4];
#pragma unroll
        for (int ni = 0; ni < 4; ++ni)
          ka[ni] = *(const bf16x8*)&Ks[p][(ni * 16 + lr) * 72 + kc * 32 + lg * 8];
#pragma unroll
        for (int ni = 0; ni < 4; ++ni)
#pragma unroll
          for (int mi = 0; mi < 2; ++mi)
            st[ni][mi] = __builtin_amdgcn_mfma_f32_16x16x32_bf16(
                ka[ni], qb[mi][kc], st[ni][mi], 0, 0, 0);
      }

      const bool mt = (kbase + 63) > (qbase + w * 32);
#pragma unroll
      for (int mi = 0; mi < 2; ++mi) {
        int qg = qbase + w * 32 + mi * 16 + lr;
        float sv[4][4];
        float tm = -1e30f;
#pragma unroll
        for (int ni = 0; ni < 4; ++ni)
#pragma unroll
          for (int r = 0; r < 4; ++r) {
            float s = st[ni][mi][r] * 0.125f;
            if (mt && (kbase + ni * 16 + lg * 4 + r) > qg) s = -1e30f;
            sv[ni][r] = s;
            tm = fmaxf(tm, s);
          }
        tm = fmaxf(tm, __shfl_xor(tm, 16));
        tm = fmaxf(tm, __shfl_xor(tm, 32));
        float mnew = fmaxf(mrow[mi], tm);
        float alpha = __expf(mrow[mi] - mnew);
        mrow[mi] = mnew;
        float sum = 0.f;
#pragma unroll
        for (int ni = 0; ni < 4; ++ni)
#pragma unroll
          for (int r = 0; r < 4; ++r) {
            float pe = __expf(sv[ni][r] - mnew);
            sv[ni][r] = pe;
            sum += pe;
          }
        sum += __shfl_xor(sum, 16);
        sum += __shfl_xor(sum, 32);
        lrow[mi] = lrow[mi] * alpha + sum;
#pragma unroll
        for (int nd = 0; nd < 4; ++nd)
#pragma unroll
          for (int r = 0; r < 4; ++r) acc[nd][mi][r] *= alpha;
        // P[q][k] packed: one b64 per (mi,ni)
#pragma unroll
        for (int ni = 0; ni < 4; ++ni) {
          uint2 wv;
          wv.x = pk2(sv[ni][0], sv[ni][1]);
          wv.y = pk2(sv[ni][2], sv[ni][3]);
          *(uint2*)&Ps[w][(mi * 16 + lr) * 72 + ni * 16 + lg * 4] = wv;
        }
      }

      // ctx^T += V^T P^T
#pragma unroll
      for (int kc = 0; kc < 2; ++kc) {
        bf16x8 pbf[2];
#pragma unroll
        for (int mi = 0; mi < 2; ++mi)
          pbf[mi] = *(const bf16x8*)&Ps[w][(mi * 16 + lr) * 72 + kc * 32 + lg * 8];
#pragma unroll
        for (int nd = 0; nd < 4; ++nd) {
          bf16x8 va = *(const bf16x8*)&Vs[p][(nd * 16 + lr) * 72 + kc * 32 + lg * 8];
#pragma unroll
          for (int mi = 0; mi < 2; ++mi)
            acc[nd][mi] = __builtin_amdgcn_mfma_f32_16x16x32_bf16(
                va, pbf[mi], acc[nd][mi], 0, 0, 0);
        }
      }
    }

    if (kt + 1 < nkt) {
      // regs (tile kt+1) -> other buffer
      *(s16x8*)&Ks[p ^ 1][srow * 72 + c0]     = rk0;
      *(s16x8*)&Ks[p ^ 1][srow * 72 + c0 + 8] = rk1;
      *(s16x8*)&Vs[p ^ 1][srow * 72 + c0]     = rv0;
      *(s16x8*)&Vs[p ^ 1][srow * 72 + c0 + 8] = rv1;
      // issue loads for tile kt+2 (land during next tile's compute)
      if (kt + 2 < nkt) {
        const unsigned short* gk = kptr + (size_t)(kt + 2) * 64 * 3072;
        const unsigned short* gv = vptr + (kt + 2) * 64;
        rk0 = *(const s16x8*)gk;  rk1 = *(const s16x8*)(gk + 8);
        rv0 = *(const s16x8*)gv;  rv1 = *(const s16x8*)(gv + 8);
      }
      __syncthreads();
      p ^= 1;
    }
  }

  // epilogue: normalize, write ctx[b, q, h*64+d] as 8B packed stores
#pragma unroll
  for (int mi = 0; mi < 2; ++mi) {
    float inv = 1.0f / lrow[mi];
    int qg = qbase + w * 32 + mi * 16 + lr;
#pragma unroll
    for (int nd = 0; nd < 4; ++nd) {
      uint2 o;
      o.x = pk2(acc[nd][mi][0] * inv, acc[nd][mi][1] * inv);
      o.y = pk2(acc[nd][mi][2] * inv, acc[nd][mi][3] * inv);
      *(uint2*)&ctx[((size_t)(b * Ss) + qg) * 1024 + h * 64 + nd * 16 + lg * 4] = o;
    }
  }
}

extern "C" void kernel_launch(void* const* d_in, const int* in_sizes, int n_in,
                              void* d_out, int out_size, void* d_ws, size_t ws_size,
                              hipStream_t stream) {
  const float* x       = (const float*)d_in[0];
  const float* w_qkv   = (const float*)d_in[1];
  const float* b_qkv   = (const float*)d_in[2];
  const float* w_dense = (const float*)d_in[3];
  const float* b_dense = (const float*)d_in[4];
  const float* fc      = (const float*)d_in[5];
  const float* fs      = (const float*)d_in[6];
  float* out = (float*)d_out;

  char* ws = (char*)d_ws;
  unsigned short* xb    = (unsigned short*)(ws);                        // 8 MB
  unsigned short* wqkvb = (unsigned short*)(ws + (8ull  << 20));        // 6 MB
  unsigned short* wdb   = (unsigned short*)(ws + (14ull << 20));        // 2 MB
  unsigned short* qkvb  = (unsigned short*)(ws + (16ull << 20));        // 24 MB
  unsigned short* vt    = (unsigned short*)(ws + (40ull << 20));        // 8 MB

  cast_f32_bf16<<<4096, 256, 0, stream>>>(x, xb, (Bb * Ss * Dd) / 4);
  cast_f32_bf16<<<3072, 256, 0, stream>>>(w_qkv, wqkvb, (3 * Dd * Dd) / 4);
  cast_f32_bf16<<<1024, 256, 0, stream>>>(w_dense, wdb, (Dd * Dd) / 4);

  gemm_bt<true><<<dim3(24, 32), 256, 0, stream>>>(xb, wqkvb, b_qkv, qkvb,
                                                  4096, 3072, 1024);
  rope_inplace<<<(Bb * Ss * Dd) / 256, 256, 0, stream>>>(qkvb, fc, fs);
  transpose_v<<<dim3(32, 32), 256, 0, stream>>>(qkvb, vt);
  attn<<<dim3(16, 32), 256, 0, stream>>>(qkvb, vt, xb /* ctx reuse */);
  gemm_bt<false><<<dim3(8, 32), 256, 0, stream>>>(xb, wdb, b_dense, out,
                                                  4096, 1024, 1024);
}

// Round 5
// 143.364 us; speedup vs baseline: 1.6780x; 1.2080x over previous
//
#include <hip/hip_runtime.h>
#include <stdint.h>

#define Bb 2
#define Ss 2048
#define Dd 1024
#define Hh 16
#define HDd 64
// M = B*S = 4096

typedef float f32x4 __attribute__((ext_vector_type(4)));
typedef __bf16 bf16x8 __attribute__((ext_vector_type(8)));
typedef short s16x8 __attribute__((ext_vector_type(8)));

__device__ inline unsigned short f2bf(float f) {
  unsigned u = __builtin_bit_cast(unsigned, f);
  u += 0x7fffu + ((u >> 16) & 1u);
  return (unsigned short)(u >> 16);
}
__device__ inline float bf2f(unsigned short h) {
  unsigned u = ((unsigned)h) << 16;
  return __builtin_bit_cast(float, u);
}
__device__ inline unsigned pk2(float a, float b) {
  return (unsigned)f2bf(a) | ((unsigned)f2bf(b) << 16);
}
// XOR-swizzled short-index into a [64-row][64-short] LDS tile (128B rows,
// eight 16B slots per row; slot ^= row&7 -> bank-balanced for all our
// read/write patterns).
__device__ inline int swz(int row, int soff) {
  return (row << 6) + ((((soff >> 3) ^ (row & 7)) << 3) | (soff & 7));
}

// ---------------- cast fp32 -> bf16, vectorized ----------------
__global__ void cast_f32_bf16(const float* __restrict__ src,
                              unsigned short* __restrict__ dst, int n4) {
  int i = blockIdx.x * blockDim.x + threadIdx.x;
  if (i < n4) {
    float4 v = ((const float4*)src)[i];
    ushort4 o;
    o.x = f2bf(v.x); o.y = f2bf(v.y); o.z = f2bf(v.z); o.w = f2bf(v.w);
    ((ushort4*)dst)[i] = o;
  }
}

// ---------------- GEMM: C[M,N] = A[M,K] * Bw[N,K]^T + bias ----------------
template <bool OUT_BF16>
__global__ __launch_bounds__(256) void gemm_bt(
    const unsigned short* __restrict__ A, const unsigned short* __restrict__ Bw,
    const float* __restrict__ bias, void* __restrict__ Cout,
    int M, int N, int K) {
  __shared__ __align__(16) unsigned short As[128 * 32];
  __shared__ __align__(16) unsigned short Bs[128 * 32];
  const int tid = threadIdx.x;
  const int w = tid >> 6, l = tid & 63;
  const int lg = l >> 4, lr = l & 15;
  const int mbase = blockIdx.y * 128, nbase = blockIdx.x * 128;
  const int wr = w >> 1, wc = w & 1;
  f32x4 acc[4][4] = {};

  for (int k0 = 0; k0 < K; k0 += 32) {
#pragma unroll
    for (int r = 0; r < 2; ++r) {
      int c = r * 256 + w * 64 + l;
      int row = c >> 2, c8 = c & 3;
      const unsigned short* ga = A + (size_t)(mbase + row) * K + k0 + c8 * 8;
      __builtin_amdgcn_global_load_lds(
          (const __attribute__((address_space(1))) void*)ga,
          (__attribute__((address_space(3))) void*)(As + c * 8), 16, 0, 0);
      const unsigned short* gb = Bw + (size_t)(nbase + row) * K + k0 + c8 * 8;
      __builtin_amdgcn_global_load_lds(
          (const __attribute__((address_space(1))) void*)gb,
          (__attribute__((address_space(3))) void*)(Bs + c * 8), 16, 0, 0);
    }
    __syncthreads();
    bf16x8 af[4], bfr[4];
#pragma unroll
    for (int mi = 0; mi < 4; ++mi)
      af[mi] = *(const bf16x8*)(As + (wr * 64 + mi * 16 + lr) * 32 + lg * 8);
#pragma unroll
    for (int ni = 0; ni < 4; ++ni)
      bfr[ni] = *(const bf16x8*)(Bs + (wc * 64 + ni * 16 + lr) * 32 + lg * 8);
#pragma unroll
    for (int mi = 0; mi < 4; ++mi)
#pragma unroll
      for (int ni = 0; ni < 4; ++ni)
        acc[mi][ni] = __builtin_amdgcn_mfma_f32_16x16x32_bf16(
            af[mi], bfr[ni], acc[mi][ni], 0, 0, 0);
    __syncthreads();
  }

#pragma unroll
  for (int mi = 0; mi < 4; ++mi) {
#pragma unroll
    for (int ni = 0; ni < 4; ++ni) {
      int col = nbase + wc * 64 + ni * 16 + lr;
      float bi = bias[col];
#pragma unroll
      for (int r = 0; r < 4; ++r) {
        int row = mbase + wr * 64 + mi * 16 + lg * 4 + r;
        float v = acc[mi][ni][r] + bi;
        if (OUT_BF16)
          ((unsigned short*)Cout)[(size_t)row * N + col] = f2bf(v);
        else
          ((float*)Cout)[(size_t)row * N + col] = v;
      }
    }
  }
}

// ---------------- RoPE in-place on q,k halves of qkv ----------------
__global__ void rope_inplace(unsigned short* __restrict__ qkv,
                             const float* __restrict__ fc,
                             const float* __restrict__ fs) {
  int j = blockIdx.x * blockDim.x + threadIdx.x;
  int m = j >> 10;
  int rr = j & 1023;
  int t = rr >> 9;
  int pp = rr & 511;
  int h = pp >> 5, p = pp & 31;
  int s = m & (Ss - 1);
  int col = t * 1024 + h * 64 + 2 * p;
  unsigned* addr = (unsigned*)(qkv + (size_t)m * 3072 + col);
  unsigned u = *addr;
  float x0 = bf2f((unsigned short)(u & 0xffff));
  float x1 = bf2f((unsigned short)(u >> 16));
  float c = fc[s * 32 + p], sn = fs[s * 32 + p];
  float o0 = x0 * c - x1 * sn;
  float o1 = x0 * sn + x1 * c;
  *addr = (unsigned)f2bf(o0) | ((unsigned)f2bf(o1) << 16);
}

// ---------------- V transpose: qkv v-part -> vt[b,h,d,s] ----------------
__global__ __launch_bounds__(256) void transpose_v(
    const unsigned short* __restrict__ qkv, unsigned short* __restrict__ vt) {
  __shared__ __align__(16) unsigned short tile[64][72];
  int s0 = blockIdx.x * 64;
  int bh = blockIdx.y;
  int b = bh >> 4, h = bh & 15;
  int t = threadIdx.x;
  int r = t >> 2, c0 = (t & 3) * 16;
  const unsigned short* src =
      qkv + (size_t)(b * Ss + s0 + r) * 3072 + 2048 + h * 64 + c0;
  *(s16x8*)&tile[r][c0]     = *(const s16x8*)src;
  *(s16x8*)&tile[r][c0 + 8] = *(const s16x8*)(src + 8);
  __syncthreads();
  unsigned short tmp[16];
#pragma unroll
  for (int i = 0; i < 16; ++i) tmp[i] = tile[c0 + i][r];
  unsigned short* dst = vt + ((size_t)bh * 64 + r) * Ss + s0 + c0;
  *(s16x8*)dst       = *(const s16x8*)tmp;
  *(s16x8*)(dst + 8) = *(const s16x8*)(tmp + 8);
}

// ---------------- Flash attention (causal), swapped-QK^T form ----------------
// 512 threads = 8 waves; wave owns 16 q-rows of a 128-row q-tile.
// Linear grid of 512 blocks, mapped so CU pairs (heavy qi=15-a, light qi=a)
// balance to a constant 34 tile-units per CU.
// All LDS tiles XOR-swizzled (16B slot ^ row&7) -> bank-balanced.
__global__ __launch_bounds__(512, 4) void attn(
    const unsigned short* __restrict__ qkv, const unsigned short* __restrict__ vt,
    unsigned short* __restrict__ ctx) {
  __shared__ __align__(16) unsigned short Ks[2][64 * 64];
  __shared__ __align__(16) unsigned short Vs[2][64 * 64];
  __shared__ __align__(16) unsigned short Ps[8][16 * 64];
  int L = blockIdx.x;
  int qi, bh;
  if (L < 256) { qi = 15 - (L & 7); bh = L >> 3; }   // heavy half, first
  else         { qi = (L - 256) & 7; bh = (L - 256) >> 3; }
  int b = bh >> 4, h = bh & 15;
  int qbase = qi * 128;
  int tid = threadIdx.x;
  int w = tid >> 6, l = tid & 63;
  int lg = l >> 4, lr = l & 15;

  // Q fragments (B-operand: col=q on lanes, k=d in regs); wave w: rows w*16..+15
  bf16x8 qb[2];
#pragma unroll
  for (int kc = 0; kc < 2; ++kc)
    qb[kc] = *(const bf16x8*)(qkv +
        (size_t)(b * Ss + qbase + w * 16 + lr) * 3072 + h * 64 + kc * 32 + lg * 8);

  // staging: thread covers tile row r, shorts [sc, sc+8)
  int r = tid >> 3, sc = (tid & 7) * 8;
  const unsigned short* kptr =
      qkv + ((size_t)(b * Ss) + r) * 3072 + 1024 + h * 64 + sc;
  const unsigned short* vptr = vt + ((size_t)bh * 64 + r) * 2048 + sc;

  int nkt = 2 * qi + 2;
  s16x8 rk, rv;
  rk = *(const s16x8*)kptr;
  rv = *(const s16x8*)vptr;
  *(s16x8*)&Ks[0][swz(r, sc)] = rk;
  *(s16x8*)&Vs[0][swz(r, sc)] = rv;
  rk = *(const s16x8*)(kptr + (size_t)64 * 3072);   // prefetch tile 1
  rv = *(const s16x8*)(vptr + 64);
  __syncthreads();

  f32x4 acc[4] = {};          // ctx^T: acc[nd], rows d, cols q(=lr)
  float mrow = -1e30f, lsum = 0.f;

  int p = 0;
  for (int kt = 0; kt < nkt; ++kt) {
    int kbase = kt * 64;
    if (kbase <= qbase + w * 16 + 15) {   // wave-uniform skip of dead tiles
      // S^T = K Q^T
      f32x4 st[4] = {};
      __builtin_amdgcn_s_setprio(1);
#pragma unroll
      for (int kc = 0; kc < 2; ++kc) {
#pragma unroll
        for (int ni = 0; ni < 4; ++ni) {
          bf16x8 ka = *(const bf16x8*)&Ks[p][swz(ni * 16 + lr, kc * 32 + lg * 8)];
          st[ni] = __builtin_amdgcn_mfma_f32_16x16x32_bf16(
              ka, qb[kc], st[ni], 0, 0, 0);
        }
      }
      __builtin_amdgcn_s_setprio(0);

      const bool mt = (kbase + 63) > (qbase + w * 16);
      int qg = qbase + w * 16 + lr;
      float sv[4][4];
      float tm = -1e30f;
#pragma unroll
      for (int ni = 0; ni < 4; ++ni)
#pragma unroll
        for (int r4 = 0; r4 < 4; ++r4) {
          float s = st[ni][r4] * 0.125f;
          if (mt && (kbase + ni * 16 + lg * 4 + r4) > qg) s = -1e30f;
          sv[ni][r4] = s;
          tm = fmaxf(tm, s);
        }
      tm = fmaxf(tm, __shfl_xor(tm, 16));
      tm = fmaxf(tm, __shfl_xor(tm, 32));
      float mnew = fmaxf(mrow, tm);
      float alpha = __expf(mrow - mnew);
      mrow = mnew;
      float sum = 0.f;
#pragma unroll
      for (int ni = 0; ni < 4; ++ni)
#pragma unroll
        for (int r4 = 0; r4 < 4; ++r4) {
          float pe = __expf(sv[ni][r4] - mnew);
          sv[ni][r4] = pe;
          sum += pe;
        }
      sum += __shfl_xor(sum, 16);
      sum += __shfl_xor(sum, 32);
      lsum = lsum * alpha + sum;
#pragma unroll
      for (int nd = 0; nd < 4; ++nd)
#pragma unroll
        for (int r4 = 0; r4 < 4; ++r4) acc[nd][r4] *= alpha;
      // P[q=lr][k] -> per-wave LDS, swizzled, one b64 per ni
#pragma unroll
      for (int ni = 0; ni < 4; ++ni) {
        uint2 wv;
        wv.x = pk2(sv[ni][0], sv[ni][1]);
        wv.y = pk2(sv[ni][2], sv[ni][3]);
        *(uint2*)&Ps[w][swz(lr, ni * 16 + lg * 4)] = wv;
      }

      // ctx^T += V^T P^T
      __builtin_amdgcn_s_setprio(1);
#pragma unroll
      for (int kc = 0; kc < 2; ++kc) {
        bf16x8 pbf = *(const bf16x8*)&Ps[w][swz(lr, kc * 32 + lg * 8)];
#pragma unroll
        for (int nd = 0; nd < 4; ++nd) {
          bf16x8 va = *(const bf16x8*)&Vs[p][swz(nd * 16 + lr, kc * 32 + lg * 8)];
          acc[nd] = __builtin_amdgcn_mfma_f32_16x16x32_bf16(
              va, pbf, acc[nd], 0, 0, 0);
        }
      }
      __builtin_amdgcn_s_setprio(0);
    }

    if (kt + 1 < nkt) {
      *(s16x8*)&Ks[p ^ 1][swz(r, sc)] = rk;     // tile kt+1 regs -> other buf
      *(s16x8*)&Vs[p ^ 1][swz(r, sc)] = rv;
      if (kt + 2 < nkt) {                       // issue loads for tile kt+2
        rk = *(const s16x8*)(kptr + (size_t)(kt + 2) * 64 * 3072);
        rv = *(const s16x8*)(vptr + (kt + 2) * 64);
      }
      __syncthreads();
      p ^= 1;
    }
  }

  // epilogue: normalize, write ctx[b, q, h*64+d] as 8B packed stores
  float inv = 1.0f / lsum;
  int qg = qbase + w * 16 + lr;
#pragma unroll
  for (int nd = 0; nd < 4; ++nd) {
    uint2 o;
    o.x = pk2(acc[nd][0] * inv, acc[nd][1] * inv);
    o.y = pk2(acc[nd][2] * inv, acc[nd][3] * inv);
    *(uint2*)&ctx[((size_t)(b * Ss) + qg) * 1024 + h * 64 + nd * 16 + lg * 4] = o;
  }
}

extern "C" void kernel_launch(void* const* d_in, const int* in_sizes, int n_in,
                              void* d_out, int out_size, void* d_ws, size_t ws_size,
                              hipStream_t stream) {
  const float* x       = (const float*)d_in[0];
  const float* w_qkv   = (const float*)d_in[1];
  const float* b_qkv   = (const float*)d_in[2];
  const float* w_dense = (const float*)d_in[3];
  const float* b_dense = (const float*)d_in[4];
  const float* fc      = (const float*)d_in[5];
  const float* fs      = (const float*)d_in[6];
  float* out = (float*)d_out;

  char* ws = (char*)d_ws;
  unsigned short* xb    = (unsigned short*)(ws);                        // 8 MB
  unsigned short* wqkvb = (unsigned short*)(ws + (8ull  << 20));        // 6 MB
  unsigned short* wdb   = (unsigned short*)(ws + (14ull << 20));        // 2 MB
  unsigned short* qkvb  = (unsigned short*)(ws + (16ull << 20));        // 24 MB
  unsigned short* vt    = (unsigned short*)(ws + (40ull << 20));        // 8 MB

  cast_f32_bf16<<<4096, 256, 0, stream>>>(x, xb, (Bb * Ss * Dd) / 4);
  cast_f32_bf16<<<3072, 256, 0, stream>>>(w_qkv, wqkvb, (3 * Dd * Dd) / 4);
  cast_f32_bf16<<<1024, 256, 0, stream>>>(w_dense, wdb, (Dd * Dd) / 4);

  gemm_bt<true><<<dim3(24, 32), 256, 0, stream>>>(xb, wqkvb, b_qkv, qkvb,
                                                  4096, 3072, 1024);
  rope_inplace<<<(Bb * Ss * Dd) / 256, 256, 0, stream>>>(qkvb, fc, fs);
  transpose_v<<<dim3(32, 32), 256, 0, stream>>>(qkvb, vt);
  attn<<<512, 512, 0, stream>>>(qkvb, vt, xb /* ctx reuse */);
  gemm_bt<false><<<dim3(8, 32), 256, 0, stream>>>(xb, wdb, b_dense, out,
                                                  4096, 1024, 1024);
}

// Round 6
// 138.953 us; speedup vs baseline: 1.7313x; 1.0317x over previous
//
#include <hip/hip_runtime.h>
#include <stdint.h>

#define Bb 2
#define Ss 2048
#define Dd 1024
#define Hh 16
#define HDd 64
// M = B*S = 4096

typedef float f32x4 __attribute__((ext_vector_type(4)));
typedef __bf16 bf16x8 __attribute__((ext_vector_type(8)));
typedef short s16x8 __attribute__((ext_vector_type(8)));

__device__ inline unsigned short f2bf(float f) {
  unsigned u = __builtin_bit_cast(unsigned, f);
  u += 0x7fffu + ((u >> 16) & 1u);
  return (unsigned short)(u >> 16);
}
__device__ inline float bf2f(unsigned short h) {
  unsigned u = ((unsigned)h) << 16;
  return __builtin_bit_cast(float, u);
}
__device__ inline unsigned pk2(float a, float b) {
  return (unsigned)f2bf(a) | ((unsigned)f2bf(b) << 16);
}
// XOR-swizzled short-index into a [64-row][64-short] LDS tile (attn).
__device__ inline int swz(int row, int soff) {
  return (row << 6) + ((((soff >> 3) ^ (row & 7)) << 3) | (soff & 7));
}

#define GLDS(dst, src)                                                        \
  __builtin_amdgcn_global_load_lds(                                           \
      (const __attribute__((address_space(1))) void*)(src),                   \
      (__attribute__((address_space(3))) void*)(dst), 16, 0, 0)

// ---------------- fused cast fp32 -> bf16 (x, w_qkv, w_dense) ----------------
// dst = ws base: xb (4194304 sh) | wqkvb (3145728 sh) | wdb (1048576 sh) contiguous.
__global__ void cast_all(const float* __restrict__ x, const float* __restrict__ wq,
                         const float* __restrict__ wd, unsigned short* __restrict__ dst) {
  int i = blockIdx.x * blockDim.x + threadIdx.x;  // float4 units
  float4 v;
  if (i < 1048576) v = ((const float4*)x)[i];
  else if (i < 1835008) v = ((const float4*)wq)[i - 1048576];
  else v = ((const float4*)wd)[i - 1835008];
  ushort4 o;
  o.x = f2bf(v.x); o.y = f2bf(v.y); o.z = f2bf(v.z); o.w = f2bf(v.w);
  ((ushort4*)dst)[i] = o;
}

// ---------------- GEMM 256x256, BK=64, 512 thr = 8 waves (2m x 4n) ----------
// Phase-pipelined (4 phases/K-tile), counted vmcnt(4) (never 0 mid-loop),
// LDS as contiguous 16KB k-half planes [buf][kc][256 rows][32 k],
// slot swizzle s' = s ^ ((row>>1)&3) applied to global SOURCE and ds_read.
template <bool OUT_BF16>
__global__ __launch_bounds__(512, 2) void gemm256(
    const unsigned short* __restrict__ A, const unsigned short* __restrict__ Bw,
    const float* __restrict__ bias, void* __restrict__ Cout,
    int M, int N, int K, int NT) {
  __shared__ __align__(16) unsigned short Asl[2][2][256 * 32];
  __shared__ __align__(16) unsigned short Bsl[2][2][256 * 32];
  const int tid = threadIdx.x;
  const int w = tid >> 6, l = tid & 63;
  const int lg = l >> 4, lr = l & 15;
  const int wm = w >> 2, wn = w & 3;
  // XCD-bijective swizzle (nwg % 8 == 0)
  int id = blockIdx.y * gridDim.x + blockIdx.x;
  const int nwg = gridDim.x * gridDim.y;
  id = (id & 7) * (nwg >> 3) + (id >> 3);
  const int bx = id % gridDim.x, by = id / gridDim.x;
  const int mbase = by * 256, nbase = bx * 256;

  // staging constants: wave w stages chunks w and w+8 of each plane
  const int r0 = w * 16 + (l >> 2);
  const int r1 = r0 + 128;
  const int sp = l & 3;
  const unsigned short* a0 = A + (size_t)(mbase + r0) * K + (sp ^ ((r0 >> 1) & 3)) * 8;
  const unsigned short* a1 = A + (size_t)(mbase + r1) * K + (sp ^ ((r1 >> 1) & 3)) * 8;
  const unsigned short* b0 = Bw + (size_t)(nbase + r0) * K + (sp ^ ((r0 >> 1) & 3)) * 8;
  const unsigned short* b1 = Bw + (size_t)(nbase + r1) * K + (sp ^ ((r1 >> 1) & 3)) * 8;
  const int d0 = w * 512 + l * 8;
  const int d1 = d0 + 4096;

  // prologue: stage tile 0, halves in order A[k0] B[k0] A[k1] B[k1]
  GLDS(&Asl[0][0][d0], a0);      GLDS(&Asl[0][0][d1], a1);
  GLDS(&Bsl[0][0][d0], b0);      GLDS(&Bsl[0][0][d1], b1);
  GLDS(&Asl[0][1][d0], a0 + 32); GLDS(&Asl[0][1][d1], a1 + 32);
  GLDS(&Bsl[0][1][d0], b0 + 32); GLDS(&Bsl[0][1][d1], b1 + 32);

  f32x4 acc[8][4] = {};
  for (int t = 0; t < NT; ++t) {
    const int cur = t & 1, nxt = cur ^ 1;
    const int kN = (t + 1) * 64;
    bf16x8 bfr[4], af[4];
    // ---------- phase (h=0, kc=0) ----------
    asm volatile("s_waitcnt vmcnt(4)" ::: "memory");
    __builtin_amdgcn_s_barrier();
    asm volatile("" ::: "memory");
#pragma unroll
    for (int ni = 0; ni < 4; ++ni) {
      int row = wn * 64 + ni * 16 + lr;
      bfr[ni] = *(const bf16x8*)(&Bsl[cur][0][row * 32 + ((lg ^ ((row >> 1) & 3)) << 3)]);
    }
#pragma unroll
    for (int j = 0; j < 4; ++j) {
      int row = wm * 128 + j * 16 + lr;
      af[j] = *(const bf16x8*)(&Asl[cur][0][row * 32 + ((lg ^ ((row >> 1) & 3)) << 3)]);
    }
    if (t + 1 < NT) { GLDS(&Asl[nxt][0][d0], a0 + kN); GLDS(&Asl[nxt][0][d1], a1 + kN); }
    __builtin_amdgcn_s_setprio(1);
#pragma unroll
    for (int j = 0; j < 4; ++j)
#pragma unroll
      for (int ni = 0; ni < 4; ++ni)
        acc[j][ni] = __builtin_amdgcn_mfma_f32_16x16x32_bf16(af[j], bfr[ni], acc[j][ni], 0, 0, 0);
    __builtin_amdgcn_s_setprio(0);
    // ---------- phase (h=1, kc=0) ----------
#pragma unroll
    for (int j = 0; j < 4; ++j) {
      int row = wm * 128 + (j + 4) * 16 + lr;
      af[j] = *(const bf16x8*)(&Asl[cur][0][row * 32 + ((lg ^ ((row >> 1) & 3)) << 3)]);
    }
    if (t + 1 < NT) { GLDS(&Bsl[nxt][0][d0], b0 + kN); GLDS(&Bsl[nxt][0][d1], b1 + kN); }
    __builtin_amdgcn_s_setprio(1);
#pragma unroll
    for (int j = 0; j < 4; ++j)
#pragma unroll
      for (int ni = 0; ni < 4; ++ni)
        acc[j + 4][ni] = __builtin_amdgcn_mfma_f32_16x16x32_bf16(af[j], bfr[ni], acc[j + 4][ni], 0, 0, 0);
    __builtin_amdgcn_s_setprio(0);
    // ---------- phase (h=0, kc=1) ----------
    if (t + 1 < NT) asm volatile("s_waitcnt vmcnt(4)" ::: "memory");
    else            asm volatile("s_waitcnt vmcnt(0)" ::: "memory");
    __builtin_amdgcn_s_barrier();
    asm volatile("" ::: "memory");
#pragma unroll
    for (int ni = 0; ni < 4; ++ni) {
      int row = wn * 64 + ni * 16 + lr;
      bfr[ni] = *(const bf16x8*)(&Bsl[cur][1][row * 32 + ((lg ^ ((row >> 1) & 3)) << 3)]);
    }
#pragma unroll
    for (int j = 0; j < 4; ++j) {
      int row = wm * 128 + j * 16 + lr;
      af[j] = *(const bf16x8*)(&Asl[cur][1][row * 32 + ((lg ^ ((row >> 1) & 3)) << 3)]);
    }
    if (t + 1 < NT) { GLDS(&Asl[nxt][1][d0], a0 + kN + 32); GLDS(&Asl[nxt][1][d1], a1 + kN + 32); }
    __builtin_amdgcn_s_setprio(1);
#pragma unroll
    for (int j = 0; j < 4; ++j)
#pragma unroll
      for (int ni = 0; ni < 4; ++ni)
        acc[j][ni] = __builtin_amdgcn_mfma_f32_16x16x32_bf16(af[j], bfr[ni], acc[j][ni], 0, 0, 0);
    __builtin_amdgcn_s_setprio(0);
    // ---------- phase (h=1, kc=1) ----------
#pragma unroll
    for (int j = 0; j < 4; ++j) {
      int row = wm * 128 + (j + 4) * 16 + lr;
      af[j] = *(const bf16x8*)(&Asl[cur][1][row * 32 + ((lg ^ ((row >> 1) & 3)) << 3)]);
    }
    if (t + 1 < NT) { GLDS(&Bsl[nxt][1][d0], b0 + kN + 32); GLDS(&Bsl[nxt][1][d1], b1 + kN + 32); }
    __builtin_amdgcn_s_setprio(1);
#pragma unroll
    for (int j = 0; j < 4; ++j)
#pragma unroll
      for (int ni = 0; ni < 4; ++ni)
        acc[j + 4][ni] = __builtin_amdgcn_mfma_f32_16x16x32_bf16(af[j], bfr[ni], acc[j + 4][ni], 0, 0, 0);
    __builtin_amdgcn_s_setprio(0);
  }

  // epilogue
#pragma unroll
  for (int mi = 0; mi < 8; ++mi)
#pragma unroll
    for (int ni = 0; ni < 4; ++ni) {
      int col = nbase + wn * 64 + ni * 16 + lr;
      float bi = bias[col];
#pragma unroll
      for (int r = 0; r < 4; ++r) {
        int row = mbase + wm * 128 + mi * 16 + lg * 4 + r;
        float v = acc[mi][ni][r] + bi;
        if (OUT_BF16)
          ((unsigned short*)Cout)[(size_t)row * N + col] = f2bf(v);
        else
          ((float*)Cout)[(size_t)row * N + col] = v;
      }
    }
}

// ---------------- GEMM: 128x128 m97 structure (kept for GEMM2, N=1024) ------
template <bool OUT_BF16>
__global__ __launch_bounds__(256) void gemm_bt(
    const unsigned short* __restrict__ A, const unsigned short* __restrict__ Bw,
    const float* __restrict__ bias, void* __restrict__ Cout,
    int M, int N, int K) {
  __shared__ __align__(16) unsigned short As[128 * 32];
  __shared__ __align__(16) unsigned short Bs[128 * 32];
  const int tid = threadIdx.x;
  const int w = tid >> 6, l = tid & 63;
  const int lg = l >> 4, lr = l & 15;
  const int mbase = blockIdx.y * 128, nbase = blockIdx.x * 128;
  const int wr = w >> 1, wc = w & 1;
  f32x4 acc[4][4] = {};

  for (int k0 = 0; k0 < K; k0 += 32) {
#pragma unroll
    for (int r = 0; r < 2; ++r) {
      int c = r * 256 + w * 64 + l;
      int row = c >> 2, c8 = c & 3;
      GLDS(As + c * 8, A + (size_t)(mbase + row) * K + k0 + c8 * 8);
      GLDS(Bs + c * 8, Bw + (size_t)(nbase + row) * K + k0 + c8 * 8);
    }
    __syncthreads();
    bf16x8 af[4], bfr[4];
#pragma unroll
    for (int mi = 0; mi < 4; ++mi)
      af[mi] = *(const bf16x8*)(As + (wr * 64 + mi * 16 + lr) * 32 + lg * 8);
#pragma unroll
    for (int ni = 0; ni < 4; ++ni)
      bfr[ni] = *(const bf16x8*)(Bs + (wc * 64 + ni * 16 + lr) * 32 + lg * 8);
#pragma unroll
    for (int mi = 0; mi < 4; ++mi)
#pragma unroll
      for (int ni = 0; ni < 4; ++ni)
        acc[mi][ni] = __builtin_amdgcn_mfma_f32_16x16x32_bf16(
            af[mi], bfr[ni], acc[mi][ni], 0, 0, 0);
    __syncthreads();
  }

#pragma unroll
  for (int mi = 0; mi < 4; ++mi) {
#pragma unroll
    for (int ni = 0; ni < 4; ++ni) {
      int col = nbase + wc * 64 + ni * 16 + lr;
      float bi = bias[col];
#pragma unroll
      for (int r = 0; r < 4; ++r) {
        int row = mbase + wr * 64 + mi * 16 + lg * 4 + r;
        float v = acc[mi][ni][r] + bi;
        if (OUT_BF16)
          ((unsigned short*)Cout)[(size_t)row * N + col] = f2bf(v);
        else
          ((float*)Cout)[(size_t)row * N + col] = v;
      }
    }
  }
}

// ---------------- RoPE in-place on q,k halves of qkv ----------------
__global__ void rope_inplace(unsigned short* __restrict__ qkv,
                             const float* __restrict__ fc,
                             const float* __restrict__ fs) {
  int j = blockIdx.x * blockDim.x + threadIdx.x;
  int m = j >> 10;
  int rr = j & 1023;
  int t = rr >> 9;
  int pp = rr & 511;
  int h = pp >> 5, p = pp & 31;
  int s = m & (Ss - 1);
  int col = t * 1024 + h * 64 + 2 * p;
  unsigned* addr = (unsigned*)(qkv + (size_t)m * 3072 + col);
  unsigned u = *addr;
  float x0 = bf2f((unsigned short)(u & 0xffff));
  float x1 = bf2f((unsigned short)(u >> 16));
  float c = fc[s * 32 + p], sn = fs[s * 32 + p];
  float o0 = x0 * c - x1 * sn;
  float o1 = x0 * sn + x1 * c;
  *addr = (unsigned)f2bf(o0) | ((unsigned)f2bf(o1) << 16);
}

// ---------------- V transpose: qkv v-part -> vt[b,h,d,s] ----------------
__global__ __launch_bounds__(256) void transpose_v(
    const unsigned short* __restrict__ qkv, unsigned short* __restrict__ vt) {
  __shared__ __align__(16) unsigned short tile[64][72];
  int s0 = blockIdx.x * 64;
  int bh = blockIdx.y;
  int b = bh >> 4, h = bh & 15;
  int t = threadIdx.x;
  int r = t >> 2, c0 = (t & 3) * 16;
  const unsigned short* src =
      qkv + (size_t)(b * Ss + s0 + r) * 3072 + 2048 + h * 64 + c0;
  *(s16x8*)&tile[r][c0]     = *(const s16x8*)src;
  *(s16x8*)&tile[r][c0 + 8] = *(const s16x8*)(src + 8);
  __syncthreads();
  unsigned short tmp[16];
#pragma unroll
  for (int i = 0; i < 16; ++i) tmp[i] = tile[c0 + i][r];
  unsigned short* dst = vt + ((size_t)bh * 64 + r) * Ss + s0 + c0;
  *(s16x8*)dst       = *(const s16x8*)tmp;
  *(s16x8*)(dst + 8) = *(const s16x8*)(tmp + 8);
}

// ---------------- Flash attention (causal), swapped-QK^T form ----------------
// 512 threads = 8 waves; wave owns 16 q-rows. Q pre-scaled by 0.125*log2e ->
// exp2-domain softmax with defer-max (THR=8). XCD remap: XCD x owns bh 4x..4x+3
// (K/V 2MB -> L2-resident), heavy q-tiles dispatched first.
__global__ __launch_bounds__(512, 4) void attn(
    const unsigned short* __restrict__ qkv, const unsigned short* __restrict__ vt,
    unsigned short* __restrict__ ctx) {
  __shared__ __align__(16) unsigned short Ks[2][64 * 64];
  __shared__ __align__(16) unsigned short Vs[2][64 * 64];
  __shared__ __align__(16) unsigned short Ps[8][16 * 64];
  int did = blockIdx.x;
  int x = did & 7, slot = did >> 3;        // slot 0..63
  int bh = x * 4 + (slot & 3);
  int s2 = slot >> 2;                      // 0..15
  int qi = (s2 < 8) ? (15 - s2) : (s2 - 8);
  int b = bh >> 4, h = bh & 15;
  int qbase = qi * 128;
  int tid = threadIdx.x;
  int w = tid >> 6, l = tid & 63;
  int lg = l >> 4, lr = l & 15;

  // Q fragments, pre-scaled into log2 domain
  bf16x8 qb[2];
#pragma unroll
  for (int kc = 0; kc < 2; ++kc) {
    s16x8 qr = *(const s16x8*)(qkv +
        (size_t)(b * Ss + qbase + w * 16 + lr) * 3072 + h * 64 + kc * 32 + lg * 8);
    bf16x8 qs;
#pragma unroll
    for (int e = 0; e < 8; ++e)
      qs[e] = (__bf16)(bf2f((unsigned short)qr[e]) * 0.18033688f);
    qb[kc] = qs;
  }

  // staging: thread covers tile row r, shorts [sc, sc+8)
  int r = tid >> 3, sc = (tid & 7) * 8;
  const unsigned short* kptr =
      qkv + ((size_t)(b * Ss) + r) * 3072 + 1024 + h * 64 + sc;
  const unsigned short* vptr = vt + ((size_t)bh * 64 + r) * 2048 + sc;

  int nkt = 2 * qi + 2;
  s16x8 rk, rv;
  rk = *(const s16x8*)kptr;
  rv = *(const s16x8*)vptr;
  *(s16x8*)&Ks[0][swz(r, sc)] = rk;
  *(s16x8*)&Vs[0][swz(r, sc)] = rv;
  rk = *(const s16x8*)(kptr + (size_t)64 * 3072);   // prefetch tile 1
  rv = *(const s16x8*)(vptr + 64);
  __syncthreads();

  f32x4 acc[4] = {};          // ctx^T: acc[nd], rows d, cols q(=lr)
  float mrow = -1e30f, lsum = 0.f;

  int p = 0;
  for (int kt = 0; kt < nkt; ++kt) {
    int kbase = kt * 64;
    if (kbase <= qbase + w * 16 + 15) {   // wave-uniform skip of dead tiles
      // S^T = K Q^T (already log2-scaled)
      f32x4 st[4] = {};
      __builtin_amdgcn_s_setprio(1);
#pragma unroll
      for (int kc = 0; kc < 2; ++kc) {
#pragma unroll
        for (int ni = 0; ni < 4; ++ni) {
          bf16x8 ka = *(const bf16x8*)&Ks[p][swz(ni * 16 + lr, kc * 32 + lg * 8)];
          st[ni] = __builtin_amdgcn_mfma_f32_16x16x32_bf16(
              ka, qb[kc], st[ni], 0, 0, 0);
        }
      }
      __builtin_amdgcn_s_setprio(0);

      const bool mt = (kbase + 63) > (qbase + w * 16);
      int qg = qbase + w * 16 + lr;
      float sv[4][4];
      float tm = -1e30f;
#pragma unroll
      for (int ni = 0; ni < 4; ++ni)
#pragma unroll
        for (int r4 = 0; r4 < 4; ++r4) {
          float s = st[ni][r4];
          if (mt && (kbase + ni * 16 + lg * 4 + r4) > qg) s = -1e30f;
          sv[ni][r4] = s;
          tm = fmaxf(tm, s);
        }
      tm = fmaxf(tm, __shfl_xor(tm, 16));
      tm = fmaxf(tm, __shfl_xor(tm, 32));
      if (!__all(tm <= mrow + 8.0f)) {     // defer-max: skip rescale if bounded
        float mnew = fmaxf(mrow, tm);
        float alpha = exp2f(mrow - mnew);
        lsum *= alpha;
#pragma unroll
        for (int nd = 0; nd < 4; ++nd)
#pragma unroll
          for (int r4 = 0; r4 < 4; ++r4) acc[nd][r4] *= alpha;
        mrow = mnew;
      }
      float sum = 0.f;
#pragma unroll
      for (int ni = 0; ni < 4; ++ni)
#pragma unroll
        for (int r4 = 0; r4 < 4; ++r4) {
          float pe = exp2f(sv[ni][r4] - mrow);
          sv[ni][r4] = pe;
          sum += pe;
        }
      sum += __shfl_xor(sum, 16);
      sum += __shfl_xor(sum, 32);
      lsum += sum;
      // P[q=lr][k] -> per-wave LDS, swizzled, one b64 per ni
#pragma unroll
      for (int ni = 0; ni < 4; ++ni) {
        uint2 wv;
        wv.x = pk2(sv[ni][0], sv[ni][1]);
        wv.y = pk2(sv[ni][2], sv[ni][3]);
        *(uint2*)&Ps[w][swz(lr, ni * 16 + lg * 4)] = wv;
      }

      // ctx^T += V^T P^T
      __builtin_amdgcn_s_setprio(1);
#pragma unroll
      for (int kc = 0; kc < 2; ++kc) {
        bf16x8 pbf = *(const bf16x8*)&Ps[w][swz(lr, kc * 32 + lg * 8)];
#pragma unroll
        for (int nd = 0; nd < 4; ++nd) {
          bf16x8 va = *(const bf16x8*)&Vs[p][swz(nd * 16 + lr, kc * 32 + lg * 8)];
          acc[nd] = __builtin_amdgcn_mfma_f32_16x16x32_bf16(
              va, pbf, acc[nd], 0, 0, 0);
        }
      }
      __builtin_amdgcn_s_setprio(0);
    }

    if (kt + 1 < nkt) {
      *(s16x8*)&Ks[p ^ 1][swz(r, sc)] = rk;     // tile kt+1 regs -> other buf
      *(s16x8*)&Vs[p ^ 1][swz(r, sc)] = rv;
      if (kt + 2 < nkt) {                       // issue loads for tile kt+2
        rk = *(const s16x8*)(kptr + (size_t)(kt + 2) * 64 * 3072);
        rv = *(const s16x8*)(vptr + (kt + 2) * 64);
      }
      __syncthreads();
      p ^= 1;
    }
  }

  // epilogue: normalize, write ctx[b, q, h*64+d] as 8B packed stores
  float inv = 1.0f / lsum;
  int qg = qbase + w * 16 + lr;
#pragma unroll
  for (int nd = 0; nd < 4; ++nd) {
    uint2 o;
    o.x = pk2(acc[nd][0] * inv, acc[nd][1] * inv);
    o.y = pk2(acc[nd][2] * inv, acc[nd][3] * inv);
    *(uint2*)&ctx[((size_t)(b * Ss) + qg) * 1024 + h * 64 + nd * 16 + lg * 4] = o;
  }
}

extern "C" void kernel_launch(void* const* d_in, const int* in_sizes, int n_in,
                              void* d_out, int out_size, void* d_ws, size_t ws_size,
                              hipStream_t stream) {
  const float* x       = (const float*)d_in[0];
  const float* w_qkv   = (const float*)d_in[1];
  const float* b_qkv   = (const float*)d_in[2];
  const float* w_dense = (const float*)d_in[3];
  const float* b_dense = (const float*)d_in[4];
  const float* fc      = (const float*)d_in[5];
  const float* fs      = (const float*)d_in[6];
  float* out = (float*)d_out;

  char* ws = (char*)d_ws;
  unsigned short* xb    = (unsigned short*)(ws);                        // 8 MB
  unsigned short* wqkvb = (unsigned short*)(ws + (8ull  << 20));        // 6 MB
  unsigned short* wdb   = (unsigned short*)(ws + (14ull << 20));        // 2 MB
  unsigned short* qkvb  = (unsigned short*)(ws + (16ull << 20));        // 24 MB
  unsigned short* vt    = (unsigned short*)(ws + (40ull << 20));        // 8 MB

  cast_all<<<8192, 256, 0, stream>>>(x, w_qkv, w_dense, xb);

  gemm256<true><<<dim3(12, 16), 512, 0, stream>>>(xb, wqkvb, b_qkv, qkvb,
                                                  4096, 3072, 1024, 16);
  rope_inplace<<<(Bb * Ss * Dd) / 256, 256, 0, stream>>>(qkvb, fc, fs);
  transpose_v<<<dim3(32, 32), 256, 0, stream>>>(qkvb, vt);
  attn<<<512, 512, 0, stream>>>(qkvb, vt, xb /* ctx reuse */);
  gemm_bt<false><<<dim3(8, 32), 256, 0, stream>>>(xb, wdb, b_dense, out,
                                                  4096, 1024, 1024);
}

// Round 7
// 125.847 us; speedup vs baseline: 1.9116x; 1.1041x over previous
//
#include <hip/hip_runtime.h>
#include <stdint.h>

#define Bb 2
#define Ss 2048
#define Dd 1024
#define Hh 16
#define HDd 64
// M = B*S = 4096

typedef float f32x4 __attribute__((ext_vector_type(4)));
typedef __bf16 bf16x8 __attribute__((ext_vector_type(8)));
typedef short s16x8 __attribute__((ext_vector_type(8)));

__device__ inline unsigned short f2bf(float f) {
  unsigned u = __builtin_bit_cast(unsigned, f);
  u += 0x7fffu + ((u >> 16) & 1u);
  return (unsigned short)(u >> 16);
}
__device__ inline float bf2f(unsigned short h) {
  unsigned u = ((unsigned)h) << 16;
  return __builtin_bit_cast(float, u);
}
__device__ inline unsigned pk2(float a, float b) {
  return (unsigned)f2bf(a) | ((unsigned)f2bf(b) << 16);
}
// native v_exp_f32 (2^x); avoid OCML precise exp2 path
__device__ inline float ex2(float x) {
#if __has_builtin(__builtin_amdgcn_exp2f)
  return __builtin_amdgcn_exp2f(x);
#else
  float r;
  asm("v_exp_f32 %0, %1\n\ts_nop 1" : "=v"(r) : "v"(x));
  return r;
#endif
}
// XOR-swizzled short-index into a [64-row][64-short] LDS tile (attn).
__device__ inline int swz(int row, int soff) {
  return (row << 6) + ((((soff >> 3) ^ (row & 7)) << 3) | (soff & 7));
}

#define GLDS(dst, src)                                                        \
  __builtin_amdgcn_global_load_lds(                                           \
      (const __attribute__((address_space(1))) void*)(src),                   \
      (__attribute__((address_space(3))) void*)(dst), 16, 0, 0)

// ---------------- fused cast fp32 -> bf16 (x, w_qkv, w_dense) ----------------
__global__ void cast_all(const float* __restrict__ x, const float* __restrict__ wq,
                         const float* __restrict__ wd, unsigned short* __restrict__ dst) {
  int i = blockIdx.x * blockDim.x + threadIdx.x;  // float4 units
  float4 v;
  if (i < 1048576) v = ((const float4*)x)[i];
  else if (i < 1835008) v = ((const float4*)wq)[i - 1048576];
  else v = ((const float4*)wd)[i - 1835008];
  ushort4 o;
  o.x = f2bf(v.x); o.y = f2bf(v.y); o.z = f2bf(v.z); o.w = f2bf(v.w);
  ((ushort4*)dst)[i] = o;
}

// ---------------- GEMM 256x256, BK=64, 512 thr = 8 waves (2m x 4n) ----------
// Phase-pipelined (4 phases/K-tile), counted vmcnt(4), slot-swizzled LDS.
// MODE 0: fp32 out + bias.  MODE 2: fused QKV epilogue -> rope(q,k)->qkv bf16,
// v -> vt[b,h,d,s] (transpose), using cos/sin tables.
template <int MODE>
__global__ __launch_bounds__(512, 2) void gemm256(
    const unsigned short* __restrict__ A, const unsigned short* __restrict__ Bw,
    const float* __restrict__ bias, void* __restrict__ Cout,
    unsigned short* __restrict__ vtout,
    const float* __restrict__ fc, const float* __restrict__ fs,
    int M, int N, int K, int NT) {
  __shared__ __align__(16) unsigned short Asl[2][2][256 * 32];
  __shared__ __align__(16) unsigned short Bsl[2][2][256 * 32];
  const int tid = threadIdx.x;
  const int w = tid >> 6, l = tid & 63;
  const int lg = l >> 4, lr = l & 15;
  const int wm = w >> 2, wn = w & 3;
  // XCD-bijective swizzle (nwg % 8 == 0)
  int id = blockIdx.y * gridDim.x + blockIdx.x;
  const int nwg = gridDim.x * gridDim.y;
  id = (id & 7) * (nwg >> 3) + (id >> 3);
  const int bx = id % gridDim.x, by = id / gridDim.x;
  const int mbase = by * 256, nbase = bx * 256;

  const int r0 = w * 16 + (l >> 2);
  const int r1 = r0 + 128;
  const int sp = l & 3;
  const unsigned short* a0 = A + (size_t)(mbase + r0) * K + (sp ^ ((r0 >> 1) & 3)) * 8;
  const unsigned short* a1 = A + (size_t)(mbase + r1) * K + (sp ^ ((r1 >> 1) & 3)) * 8;
  const unsigned short* b0 = Bw + (size_t)(nbase + r0) * K + (sp ^ ((r0 >> 1) & 3)) * 8;
  const unsigned short* b1 = Bw + (size_t)(nbase + r1) * K + (sp ^ ((r1 >> 1) & 3)) * 8;
  const int d0 = w * 512 + l * 8;
  const int d1 = d0 + 4096;

  GLDS(&Asl[0][0][d0], a0);      GLDS(&Asl[0][0][d1], a1);
  GLDS(&Bsl[0][0][d0], b0);      GLDS(&Bsl[0][0][d1], b1);
  GLDS(&Asl[0][1][d0], a0 + 32); GLDS(&Asl[0][1][d1], a1 + 32);
  GLDS(&Bsl[0][1][d0], b0 + 32); GLDS(&Bsl[0][1][d1], b1 + 32);

  f32x4 acc[8][4] = {};
  for (int t = 0; t < NT; ++t) {
    const int cur = t & 1, nxt = cur ^ 1;
    const int kN = (t + 1) * 64;
    bf16x8 bfr[4], af[4];
    // ---------- phase (h=0, kc=0) ----------
    asm volatile("s_waitcnt vmcnt(4)" ::: "memory");
    __builtin_amdgcn_s_barrier();
    asm volatile("" ::: "memory");
#pragma unroll
    for (int ni = 0; ni < 4; ++ni) {
      int row = wn * 64 + ni * 16 + lr;
      bfr[ni] = *(const bf16x8*)(&Bsl[cur][0][row * 32 + ((lg ^ ((row >> 1) & 3)) << 3)]);
    }
#pragma unroll
    for (int j = 0; j < 4; ++j) {
      int row = wm * 128 + j * 16 + lr;
      af[j] = *(const bf16x8*)(&Asl[cur][0][row * 32 + ((lg ^ ((row >> 1) & 3)) << 3)]);
    }
    if (t + 1 < NT) { GLDS(&Asl[nxt][0][d0], a0 + kN); GLDS(&Asl[nxt][0][d1], a1 + kN); }
    __builtin_amdgcn_s_setprio(1);
#pragma unroll
    for (int j = 0; j < 4; ++j)
#pragma unroll
      for (int ni = 0; ni < 4; ++ni)
        acc[j][ni] = __builtin_amdgcn_mfma_f32_16x16x32_bf16(af[j], bfr[ni], acc[j][ni], 0, 0, 0);
    __builtin_amdgcn_s_setprio(0);
    // ---------- phase (h=1, kc=0) ----------
#pragma unroll
    for (int j = 0; j < 4; ++j) {
      int row = wm * 128 + (j + 4) * 16 + lr;
      af[j] = *(const bf16x8*)(&Asl[cur][0][row * 32 + ((lg ^ ((row >> 1) & 3)) << 3)]);
    }
    if (t + 1 < NT) { GLDS(&Bsl[nxt][0][d0], b0 + kN); GLDS(&Bsl[nxt][0][d1], b1 + kN); }
    __builtin_amdgcn_s_setprio(1);
#pragma unroll
    for (int j = 0; j < 4; ++j)
#pragma unroll
      for (int ni = 0; ni < 4; ++ni)
        acc[j + 4][ni] = __builtin_amdgcn_mfma_f32_16x16x32_bf16(af[j], bfr[ni], acc[j + 4][ni], 0, 0, 0);
    __builtin_amdgcn_s_setprio(0);
    // ---------- phase (h=0, kc=1) ----------
    if (t + 1 < NT) asm volatile("s_waitcnt vmcnt(4)" ::: "memory");
    else            asm volatile("s_waitcnt vmcnt(0)" ::: "memory");
    __builtin_amdgcn_s_barrier();
    asm volatile("" ::: "memory");
#pragma unroll
    for (int ni = 0; ni < 4; ++ni) {
      int row = wn * 64 + ni * 16 + lr;
      bfr[ni] = *(const bf16x8*)(&Bsl[cur][1][row * 32 + ((lg ^ ((row >> 1) & 3)) << 3)]);
    }
#pragma unroll
    for (int j = 0; j < 4; ++j) {
      int row = wm * 128 + j * 16 + lr;
      af[j] = *(const bf16x8*)(&Asl[cur][1][row * 32 + ((lg ^ ((row >> 1) & 3)) << 3)]);
    }
    if (t + 1 < NT) { GLDS(&Asl[nxt][1][d0], a0 + kN + 32); GLDS(&Asl[nxt][1][d1], a1 + kN + 32); }
    __builtin_amdgcn_s_setprio(1);
#pragma unroll
    for (int j = 0; j < 4; ++j)
#pragma unroll
      for (int ni = 0; ni < 4; ++ni)
        acc[j][ni] = __builtin_amdgcn_mfma_f32_16x16x32_bf16(af[j], bfr[ni], acc[j][ni], 0, 0, 0);
    __builtin_amdgcn_s_setprio(0);
    // ---------- phase (h=1, kc=1) ----------
#pragma unroll
    for (int j = 0; j < 4; ++j) {
      int row = wm * 128 + (j + 4) * 16 + lr;
      af[j] = *(const bf16x8*)(&Asl[cur][1][row * 32 + ((lg ^ ((row >> 1) & 3)) << 3)]);
    }
    if (t + 1 < NT) { GLDS(&Bsl[nxt][1][d0], b0 + kN + 32); GLDS(&Bsl[nxt][1][d1], b1 + kN + 32); }
    __builtin_amdgcn_s_setprio(1);
#pragma unroll
    for (int j = 0; j < 4; ++j)
#pragma unroll
      for (int ni = 0; ni < 4; ++ni)
        acc[j + 4][ni] = __builtin_amdgcn_mfma_f32_16x16x32_bf16(af[j], bfr[ni], acc[j + 4][ni], 0, 0, 0);
    __builtin_amdgcn_s_setprio(0);
  }

  // ---------------- epilogue ----------------
#pragma unroll
  for (int mi = 0; mi < 8; ++mi)
#pragma unroll
    for (int ni = 0; ni < 4; ++ni) {
      int col = nbase + wn * 64 + ni * 16 + lr;
      float bi = bias[col];
      int row0 = mbase + wm * 128 + mi * 16 + lg * 4;
      float o4[4];
#pragma unroll
      for (int r = 0; r < 4; ++r) o4[r] = acc[mi][ni][r] + bi;
      if constexpr (MODE == 0) {
#pragma unroll
        for (int r = 0; r < 4; ++r)
          ((float*)Cout)[(size_t)(row0 + r) * N + col] = o4[r];
      } else {
        int sect = col >> 10;          // wave-uniform (col indep of lg)
        int d = col & 63;
        int srow0 = row0 & 2047;
        if (sect < 2) {
          // RoPE: pair partner is lane lr^1 (col^1)
          int p = d >> 1;
#pragma unroll
          for (int r = 0; r < 4; ++r) {
            float vp = __shfl_xor(o4[r], 1);
            float c = fc[(srow0 + r) * 32 + p];
            float s = fs[(srow0 + r) * 32 + p];
            float o = (d & 1) ? (vp * s + o4[r] * c) : (o4[r] * c - vp * s);
            ((unsigned short*)Cout)[(size_t)(row0 + r) * 3072 + col] = f2bf(o);
          }
        } else {
          // V -> vt[b,h,d,s], 4 consecutive s packed into one 8B store
          int bh = (row0 >> 11) * 16 + ((col >> 6) & 15);
          uint2 o;
          o.x = pk2(o4[0], o4[1]);
          o.y = pk2(o4[2], o4[3]);
          *(uint2*)&vtout[((size_t)(bh * 64 + d)) * 2048 + srow0] = o;
        }
      }
    }
}

// ---------------- GEMM: 128x128 m97 structure (GEMM2, fp32 out) ------
__global__ __launch_bounds__(256) void gemm_bt(
    const unsigned short* __restrict__ A, const unsigned short* __restrict__ Bw,
    const float* __restrict__ bias, float* __restrict__ Cout,
    int M, int N, int K) {
  __shared__ __align__(16) unsigned short As[128 * 32];
  __shared__ __align__(16) unsigned short Bs[128 * 32];
  const int tid = threadIdx.x;
  const int w = tid >> 6, l = tid & 63;
  const int lg = l >> 4, lr = l & 15;
  const int mbase = blockIdx.y * 128, nbase = blockIdx.x * 128;
  const int wr = w >> 1, wc = w & 1;
  f32x4 acc[4][4] = {};

  for (int k0 = 0; k0 < K; k0 += 32) {
#pragma unroll
    for (int r = 0; r < 2; ++r) {
      int c = r * 256 + w * 64 + l;
      int row = c >> 2, c8 = c & 3;
      GLDS(As + c * 8, A + (size_t)(mbase + row) * K + k0 + c8 * 8);
      GLDS(Bs + c * 8, Bw + (size_t)(nbase + row) * K + k0 + c8 * 8);
    }
    __syncthreads();
    bf16x8 af[4], bfr[4];
#pragma unroll
    for (int mi = 0; mi < 4; ++mi)
      af[mi] = *(const bf16x8*)(As + (wr * 64 + mi * 16 + lr) * 32 + lg * 8);
#pragma unroll
    for (int ni = 0; ni < 4; ++ni)
      bfr[ni] = *(const bf16x8*)(Bs + (wc * 64 + ni * 16 + lr) * 32 + lg * 8);
#pragma unroll
    for (int mi = 0; mi < 4; ++mi)
#pragma unroll
      for (int ni = 0; ni < 4; ++ni)
        acc[mi][ni] = __builtin_amdgcn_mfma_f32_16x16x32_bf16(
            af[mi], bfr[ni], acc[mi][ni], 0, 0, 0);
    __syncthreads();
  }

#pragma unroll
  for (int mi = 0; mi < 4; ++mi) {
#pragma unroll
    for (int ni = 0; ni < 4; ++ni) {
      int col = nbase + wc * 64 + ni * 16 + lr;
      float bi = bias[col];
#pragma unroll
      for (int r = 0; r < 4; ++r) {
        int row = mbase + wr * 64 + mi * 16 + lg * 4 + r;
        Cout[(size_t)row * N + col] = acc[mi][ni][r] + bi;
      }
    }
  }
}

// ---------------- Flash attention (causal), swapped-QK^T form ----------------
// 512 threads = 8 waves; wave owns 16 q-rows. Q pre-scaled by 0.125*log2e ->
// exp2-domain softmax (native v_exp_f32) with defer-max (THR=8).
// XCD remap: XCD x owns bh 4x..4x+3 (K/V L2-resident), heavy q-tiles first.
__global__ __launch_bounds__(512, 4) void attn(
    const unsigned short* __restrict__ qkv, const unsigned short* __restrict__ vt,
    unsigned short* __restrict__ ctx) {
  __shared__ __align__(16) unsigned short Ks[2][64 * 64];
  __shared__ __align__(16) unsigned short Vs[2][64 * 64];
  __shared__ __align__(16) unsigned short Ps[8][16 * 64];
  int did = blockIdx.x;
  int x = did & 7, slot = did >> 3;        // slot 0..63
  int bh = x * 4 + (slot & 3);
  int s2 = slot >> 2;                      // 0..15
  int qi = (s2 < 8) ? (15 - s2) : (s2 - 8);
  int b = bh >> 4, h = bh & 15;
  int qbase = qi * 128;
  int tid = threadIdx.x;
  int w = tid >> 6, l = tid & 63;
  int lg = l >> 4, lr = l & 15;

  // Q fragments, pre-scaled into log2 domain
  bf16x8 qb[2];
#pragma unroll
  for (int kc = 0; kc < 2; ++kc) {
    s16x8 qr = *(const s16x8*)(qkv +
        (size_t)(b * Ss + qbase + w * 16 + lr) * 3072 + h * 64 + kc * 32 + lg * 8);
    bf16x8 qs;
#pragma unroll
    for (int e = 0; e < 8; ++e)
      qs[e] = (__bf16)(bf2f((unsigned short)qr[e]) * 0.18033688f);
    qb[kc] = qs;
  }

  // staging: thread covers tile row r, shorts [sc, sc+8)
  int r = tid >> 3, sc = (tid & 7) * 8;
  const unsigned short* kptr =
      qkv + ((size_t)(b * Ss) + r) * 3072 + 1024 + h * 64 + sc;
  const unsigned short* vptr = vt + ((size_t)bh * 64 + r) * 2048 + sc;

  int nkt = 2 * qi + 2;
  s16x8 rk, rv;
  rk = *(const s16x8*)kptr;
  rv = *(const s16x8*)vptr;
  *(s16x8*)&Ks[0][swz(r, sc)] = rk;
  *(s16x8*)&Vs[0][swz(r, sc)] = rv;
  rk = *(const s16x8*)(kptr + (size_t)64 * 3072);   // prefetch tile 1
  rv = *(const s16x8*)(vptr + 64);
  __syncthreads();

  f32x4 acc[4] = {};          // ctx^T: acc[nd], rows d, cols q(=lr)
  float mrow = -1e30f, lsum = 0.f;

  int p = 0;
  for (int kt = 0; kt < nkt; ++kt) {
    int kbase = kt * 64;
    if (kbase <= qbase + w * 16 + 15) {   // wave-uniform skip of dead tiles
      // S^T = K Q^T (already log2-scaled)
      f32x4 st[4] = {};
      __builtin_amdgcn_s_setprio(1);
#pragma unroll
      for (int kc = 0; kc < 2; ++kc) {
#pragma unroll
        for (int ni = 0; ni < 4; ++ni) {
          bf16x8 ka = *(const bf16x8*)&Ks[p][swz(ni * 16 + lr, kc * 32 + lg * 8)];
          st[ni] = __builtin_amdgcn_mfma_f32_16x16x32_bf16(
              ka, qb[kc], st[ni], 0, 0, 0);
        }
      }
      __builtin_amdgcn_s_setprio(0);

      const bool mt = (kbase + 63) > (qbase + w * 16);
      int qg = qbase + w * 16 + lr;
      float sv[4][4];
      float tm = -1e30f;
#pragma unroll
      for (int ni = 0; ni < 4; ++ni)
#pragma unroll
        for (int r4 = 0; r4 < 4; ++r4) {
          float s = st[ni][r4];
          if (mt && (kbase + ni * 16 + lg * 4 + r4) > qg) s = -1e30f;
          sv[ni][r4] = s;
          tm = fmaxf(tm, s);
        }
      tm = fmaxf(tm, __shfl_xor(tm, 16));
      tm = fmaxf(tm, __shfl_xor(tm, 32));
      if (!__all(tm <= mrow + 8.0f)) {     // defer-max: skip rescale if bounded
        float mnew = fmaxf(mrow, tm);
        float alpha = ex2(mrow - mnew);
        lsum *= alpha;
#pragma unroll
        for (int nd = 0; nd < 4; ++nd)
#pragma unroll
          for (int r4 = 0; r4 < 4; ++r4) acc[nd][r4] *= alpha;
        mrow = mnew;
      }
      float sum = 0.f;
#pragma unroll
      for (int ni = 0; ni < 4; ++ni)
#pragma unroll
        for (int r4 = 0; r4 < 4; ++r4) {
          float pe = ex2(sv[ni][r4] - mrow);
          sv[ni][r4] = pe;
          sum += pe;
        }
      sum += __shfl_xor(sum, 16);
      sum += __shfl_xor(sum, 32);
      lsum += sum;
      // P[q=lr][k] -> per-wave LDS, swizzled, one b64 per ni
#pragma unroll
      for (int ni = 0; ni < 4; ++ni) {
        uint2 wv;
        wv.x = pk2(sv[ni][0], sv[ni][1]);
        wv.y = pk2(sv[ni][2], sv[ni][3]);
        *(uint2*)&Ps[w][swz(lr, ni * 16 + lg * 4)] = wv;
      }

      // ctx^T += V^T P^T
      __builtin_amdgcn_s_setprio(1);
#pragma unroll
      for (int kc = 0; kc < 2; ++kc) {
        bf16x8 pbf = *(const bf16x8*)&Ps[w][swz(lr, kc * 32 + lg * 8)];
#pragma unroll
        for (int nd = 0; nd < 4; ++nd) {
          bf16x8 va = *(const bf16x8*)&Vs[p][swz(nd * 16 + lr, kc * 32 + lg * 8)];
          acc[nd] = __builtin_amdgcn_mfma_f32_16x16x32_bf16(
              va, pbf, acc[nd], 0, 0, 0);
        }
      }
      __builtin_amdgcn_s_setprio(0);
    }

    if (kt + 1 < nkt) {
      *(s16x8*)&Ks[p ^ 1][swz(r, sc)] = rk;     // tile kt+1 regs -> other buf
      *(s16x8*)&Vs[p ^ 1][swz(r, sc)] = rv;
      if (kt + 2 < nkt) {                       // issue loads for tile kt+2
        rk = *(const s16x8*)(kptr + (size_t)(kt + 2) * 64 * 3072);
        rv = *(const s16x8*)(vptr + (kt + 2) * 64);
      }
      __syncthreads();
      p ^= 1;
    }
  }

  // epilogue: normalize, write ctx[b, q, h*64+d] as 8B packed stores
  float inv = 1.0f / lsum;
  int qg = qbase + w * 16 + lr;
#pragma unroll
  for (int nd = 0; nd < 4; ++nd) {
    uint2 o;
    o.x = pk2(acc[nd][0] * inv, acc[nd][1] * inv);
    o.y = pk2(acc[nd][2] * inv, acc[nd][3] * inv);
    *(uint2*)&ctx[((size_t)(b * Ss) + qg) * 1024 + h * 64 + nd * 16 + lg * 4] = o;
  }
}

extern "C" void kernel_launch(void* const* d_in, const int* in_sizes, int n_in,
                              void* d_out, int out_size, void* d_ws, size_t ws_size,
                              hipStream_t stream) {
  const float* x       = (const float*)d_in[0];
  const float* w_qkv   = (const float*)d_in[1];
  const float* b_qkv   = (const float*)d_in[2];
  const float* w_dense = (const float*)d_in[3];
  const float* b_dense = (const float*)d_in[4];
  const float* fc      = (const float*)d_in[5];
  const float* fs      = (const float*)d_in[6];
  float* out = (float*)d_out;

  char* ws = (char*)d_ws;
  unsigned short* xb    = (unsigned short*)(ws);                        // 8 MB
  unsigned short* wqkvb = (unsigned short*)(ws + (8ull  << 20));        // 6 MB
  unsigned short* wdb   = (unsigned short*)(ws + (14ull << 20));        // 2 MB
  unsigned short* qkvb  = (unsigned short*)(ws + (16ull << 20));        // 24 MB
  unsigned short* vt    = (unsigned short*)(ws + (40ull << 20));        // 8 MB

  cast_all<<<8192, 256, 0, stream>>>(x, w_qkv, w_dense, xb);

  // GEMM1 fused: rope(q,k) -> qkvb ; v -> vt (transposed)
  gemm256<2><<<dim3(12, 16), 512, 0, stream>>>(xb, wqkvb, b_qkv, qkvb, vt,
                                               fc, fs, 4096, 3072, 1024, 16);
  attn<<<512, 512, 0, stream>>>(qkvb, vt, xb /* ctx reuse */);
  gemm_bt<<<dim3(8, 32), 256, 0, stream>>>(xb, wdb, b_dense, out,
                                           4096, 1024, 1024);
}